// Round 1
// baseline (161.948 us; speedup 1.0000x reference)
//
#include <hip/hip_runtime.h>

#define N_ 512
#define D_ 128
#define LOG2E 1.44269504088896f

// ws: [0, 8 MB)    xp_t bf16 TRANSPOSED [inst][f=128][s=512]       (8,388,608 B)
//     [8, 9 MB)    sgE u32 [inst][h=8][s=512]  (Es|Fs packed bf16) (1,048,576 B)
//     [9, 11 MB)   sgD float2 [inst][h=8][s=512] (Ed, Fd fp32)     (2,097,152 B)
//     [11, 13 MB)  mask_g u16 [inst][tile=32][s=512]               (2,097,152 B)
// Factorized softmax: w = exp(leaky(ss+sd)) = max(Es*Ed, Fs*Fd); per-dst
// scale Ed cancels in Cacc/Cz, so the K-loop uses w' = max(Es, Fs*rd),
// masked w' = 1/Ed — NO transcendentals in the hot loop.
// d_out zeroed, conv contributions atomically added (2 adders/address,
// deterministic), combine mixes in place.

typedef __attribute__((ext_vector_type(8))) short short8;
typedef __attribute__((ext_vector_type(4))) float floatx4;
typedef __attribute__((ext_vector_type(4))) unsigned int uintx4;

#if defined(__has_builtin)
#if __has_builtin(__builtin_amdgcn_exp2f)
#define EXP2F(x) __builtin_amdgcn_exp2f(x)
#else
#define EXP2F(x) exp2f(x)
#endif
#else
#define EXP2F(x) exp2f(x)
#endif

__device__ __forceinline__ unsigned short f2bf(float f) {
    unsigned int u = __float_as_uint(f);
    u += 0x7fffu + ((u >> 16) & 1u);
    return (unsigned short)(u >> 16);
}
__device__ __forceinline__ float bflo(unsigned int u) { return __uint_as_float(u << 16); }
__device__ __forceinline__ float bfhi(unsigned int u) { return __uint_as_float(u & 0xffff0000u); }

// ---------------------------------------------------------------------------
// Kernel 1 (fused prep): blocks 0..1023 = proj (MFMA, no LDS/barriers, fused
// score reductions -> Es/Fs packed bf16 + Ed/Fd fp32); blocks 1024..2047 =
// maskprep (A -> per-tile u16 edge bitmasks). Independent work, one dispatch.
// ---------------------------------------------------------------------------
__global__ __launch_bounds__(256) void prep_kernel(
    const float* __restrict__ x, const float* __restrict__ W,
    const float* __restrict__ pb, const float* __restrict__ att_src,
    const float* __restrict__ att_dst, const int* __restrict__ A,
    unsigned short* __restrict__ xpt, unsigned int* __restrict__ sgE,
    float2* __restrict__ sgD, unsigned short* __restrict__ mg)
{
    const int bid0 = blockIdx.x;
    const int t = threadIdx.x;

    if (bid0 >= 1024) {
        // ------------- maskprep: block = (bi, 16-s tile) -------------
        const int bid = bid0 - 1024;
        const int stile = bid & 31;
        const int bi = bid >> 5;
        const int sl = t >> 4, lane = t & 15;
        const int s = stile * 16 + sl;
        const int* Ar = A + ((size_t)bi * N_ + s) * N_ + lane * 32;
        unsigned int m0 = 0, m1 = 0;
#pragma unroll
        for (int g = 0; g < 8; ++g) {
            const int4 v = *(const int4*)(Ar + g * 4);
            const int k = g * 4;
            if (v.x == 2 || v.x == 4) m0 |= 1u << (k + 0);
            if (v.x == 3 || v.x == 4) m1 |= 1u << (k + 0);
            if (v.y == 2 || v.y == 4) m0 |= 1u << (k + 1);
            if (v.y == 3 || v.y == 4) m1 |= 1u << (k + 1);
            if (v.z == 2 || v.z == 4) m0 |= 1u << (k + 2);
            if (v.z == 3 || v.z == 4) m1 |= 1u << (k + 2);
            if (v.w == 2 || v.w == 4) m0 |= 1u << (k + 3);
            if (v.w == 3 || v.w == 4) m1 |= 1u << (k + 3);
        }
        const size_t b0 = ((size_t)bi * 2 + 0) * 32 * N_;
        const size_t b1 = ((size_t)bi * 2 + 1) * 32 * N_;
        const int T0 = lane * 2, T1 = lane * 2 + 1;
        mg[b0 + (size_t)T0 * N_ + s] = (unsigned short)(m0 & 0xFFFFu);
        mg[b0 + (size_t)T1 * N_ + s] = (unsigned short)(m0 >> 16);
        mg[b1 + (size_t)T0 * N_ + s] = (unsigned short)(m1 & 0xFFFFu);
        mg[b1 + (size_t)T1 * N_ + s] = (unsigned short)(m1 >> 16);
        return;
    }

    // ------------- proj: 2 blocks per (inst, 64-row ntile) -------------
    const int unit = bid0 >> 1;
    const int half = bid0 & 1;
    const int ntile = unit & 7;
    const int inst  = unit >> 3;
    const int j = inst & 1;
    const int bi = inst >> 1;
    const int ij = (bi & 1) * 2 + j;
    const int wave = t >> 6, L = t & 63, n = L & 15, q = L >> 4;

    const int n0w = ntile * 64 + wave * 16;
    const float* xrow = x + ((size_t)bi * N_ + n0w + n) * D_ + q * 8;
    short8 Af[4];
#pragma unroll
    for (int kc = 0; kc < 4; ++kc) {
        const float4 a0 = *(const float4*)(xrow + kc * 32);
        const float4 a1 = *(const float4*)(xrow + kc * 32 + 4);
        uintx4 au;
        au.x = f2bf(a0.x) | ((unsigned int)f2bf(a0.y) << 16);
        au.y = f2bf(a0.z) | ((unsigned int)f2bf(a0.w) << 16);
        au.z = f2bf(a1.x) | ((unsigned int)f2bf(a1.y) << 16);
        au.w = f2bf(a1.z) | ((unsigned int)f2bf(a1.w) << 16);
        Af[kc] = __builtin_bit_cast(short8, au);
    }

    const float* wb = W + (size_t)ij * D_ * D_;
#pragma unroll
    for (int ft = 0; ft < 4; ++ft) {
        const int head = half * 4 + ft;
        const int fg = head * 16 + n;
        const float* wrow = wb + (size_t)fg * D_ + q * 8;
        floatx4 C = (floatx4){0.f, 0.f, 0.f, 0.f};
#pragma unroll
        for (int kc = 0; kc < 4; ++kc) {
            const float4 b0 = *(const float4*)(wrow + kc * 32);
            const float4 b1 = *(const float4*)(wrow + kc * 32 + 4);
            uintx4 bu;
            bu.x = f2bf(b0.x) | ((unsigned int)f2bf(b0.y) << 16);
            bu.y = f2bf(b0.z) | ((unsigned int)f2bf(b0.w) << 16);
            bu.z = f2bf(b1.x) | ((unsigned int)f2bf(b1.y) << 16);
            bu.w = f2bf(b1.z) | ((unsigned int)f2bf(b1.w) << 16);
            C = __builtin_amdgcn_mfma_f32_16x16x32_bf16(
                Af[kc], __builtin_bit_cast(short8, bu), C, 0, 0, 0);
        }
        const float pbv = pb[ij * D_ + fg];
        float xp0 = C[0] + pbv, xp1 = C[1] + pbv;
        float xp2 = C[2] + pbv, xp3 = C[3] + pbv;
        uint2 pk;
        pk.x = f2bf(xp0) | ((unsigned int)f2bf(xp1) << 16);
        pk.y = f2bf(xp2) | ((unsigned int)f2bf(xp3) << 16);
        *(uint2*)&xpt[((size_t)inst * D_ + fg) * N_ + n0w + q * 4] = pk;

        const float asv = att_src[ij * D_ + fg];
        const float adv = att_dst[ij * D_ + fg];
        float sa0 = xp0 * asv, sa1 = xp1 * asv, sa2 = xp2 * asv, sa3 = xp3 * asv;
        float sb0 = xp0 * adv, sb1 = xp1 * adv, sb2 = xp2 * adv, sb3 = xp3 * adv;
#pragma unroll
        for (int off = 1; off < 16; off <<= 1) {
            sa0 += __shfl_xor(sa0, off); sa1 += __shfl_xor(sa1, off);
            sa2 += __shfl_xor(sa2, off); sa3 += __shfl_xor(sa3, off);
            sb0 += __shfl_xor(sb0, off); sb1 += __shfl_xor(sb1, off);
            sb2 += __shfl_xor(sb2, off); sb3 += __shfl_xor(sb3, off);
        }
        if (n < 4) {   // Es|Fs packed bf16: e^ss, e^{0.2 ss}
            const float v = ((n == 0) ? sa0 : (n == 1) ? sa1 : (n == 2) ? sa2 : sa3) * LOG2E;
            const unsigned int pkv = f2bf(EXP2F(v)) |
                ((unsigned int)f2bf(EXP2F(0.2f * v)) << 16);
            sgE[((size_t)inst * 8 + head) * N_ + n0w + q * 4 + n] = pkv;
        } else if (n >= 8 && n < 12) {   // Ed, Fd fp32
            const int r = n - 8;
            const float v = ((r == 0) ? sb0 : (r == 1) ? sb1 : (r == 2) ? sb2 : sb3) * LOG2E;
            float2 ed;
            ed.x = EXP2F(v);
            ed.y = EXP2F(0.2f * v);
            sgD[((size_t)inst * 8 + head) * N_ + n0w + q * 4 + r] = ed;
        }
    }
}

// ---------------------------------------------------------------------------
// Kernel 2: attention via MFMA, split by conv, factorized softmax. 2048
// blocks: tile = bid&31, conv = (bid>>5)&1, bi = bid>>6. 4 waves, wave owns
// 2 heads. LDS 17.25 KB -> 8 blocks/CU. K-loop: w' = max(Es, Fs*rd), masked
// w' = 1/Ed (per-dst scale cancels in Cacc/Cz) — no exp in the loop. Z via
// second MFMA vs all-ones B; v_perm pack truncates w' to bf16 so Z and
// numerator match. unsafeAtomicAdd into zeroed d_out. ONE __syncthreads.
// ---------------------------------------------------------------------------
__global__ __launch_bounds__(256) void attn_kernel(
    const unsigned short* __restrict__ xpt,
    const unsigned int* __restrict__ sgE,
    const float2* __restrict__ sgD,
    const unsigned short* __restrict__ mg,
    const float* __restrict__ bias,
    float* __restrict__ hout)
{
    __shared__ unsigned int es_l[8 * N_];   // 16 KB [h][s] (Es|Fs bf16 pair)
    __shared__ unsigned short mask_l[N_];   // 1 KB

    const int bid = blockIdx.x;
    const int tile = bid & 31;
    const int cj   = (bid >> 5) & 1;
    const int bi   = bid >> 6;
    const int inst = bi * 2 + cj;
    const int ij = (bi & 1) * 2 + cj;
    const int d0 = tile * 16;
    const int t = threadIdx.x;
    const int wave = t >> 6, L = t & 63, n = L & 15, q = L >> 4;
    const int h0 = wave * 2;
    const int n16 = n + 16;

    // stage Es|Fs (4096 u32) + masks (512 u16)
    {
        const uint4* src = (const uint4*)(sgE + (size_t)inst * 8 * N_);
        uint4* dst = (uint4*)es_l;
#pragma unroll
        for (int r = 0; r < 4; ++r) dst[r * 256 + t] = src[r * 256 + t];
    }
    if (t < 64)
        ((uint4*)mask_l)[t] =
            ((const uint4*)(mg + ((size_t)inst * 32 + tile) * N_))[t];

    // per-(hh) dst factors: iEd = 1/Ed, rd = Fd/Ed
    float iEd[2], rd[2];
#pragma unroll
    for (int hh = 0; hh < 2; ++hh) {
        const float2 ed = sgD[((size_t)inst * 8 + h0 + hh) * N_ + d0 + n];
        iEd[hh] = 1.0f / ed.x;
        rd[hh] = ed.y * iEd[hh];
    }

    __syncthreads();   // the ONLY barrier

    const unsigned short* xpi = xpt + (size_t)inst * D_ * N_;

    const uintx4 ou = { 0x3F803F80u, 0x3F803F80u, 0x3F803F80u, 0x3F803F80u };
    const short8 onesB = __builtin_bit_cast(short8, ou);

    floatx4 Cacc[2] = { (floatx4){0.f,0.f,0.f,0.f}, (floatx4){0.f,0.f,0.f,0.f} };
    floatx4 Cz[2]   = { (floatx4){0.f,0.f,0.f,0.f}, (floatx4){0.f,0.f,0.f,0.f} };

    // software-prefetched, barrier-free K loop: 16 chunks of 32 s
    short8 Bf0 = *(const short8*)(xpi + (size_t)(h0 * 16 + n) * N_ + q * 8);
    short8 Bf1 = *(const short8*)(xpi + (size_t)((h0 + 1) * 16 + n) * N_ + q * 8);
    for (int c = 0; c < 16; ++c) {
        const int sq = c * 32 + q * 8;
        short8 nB0, nB1;
        if (c < 15) {
            nB0 = *(const short8*)(xpi + (size_t)(h0 * 16 + n) * N_ + sq + 32);
            nB1 = *(const short8*)(xpi + (size_t)((h0 + 1) * 16 + n) * N_ + sq + 32);
        }
        const uint4 mv = *(const uint4*)&mask_l[sq];   // 8 u16 masks
        const unsigned int mw[4] = { mv.x, mv.y, mv.z, mv.w };
#pragma unroll
        for (int hh = 0; hh < 2; ++hh) {
            const uint4 e0 = *(const uint4*)&es_l[(h0 + hh) * N_ + sq];
            const uint4 e1 = *(const uint4*)&es_l[(h0 + hh) * N_ + sq + 4];
            const unsigned int epk[8] = { e0.x, e0.y, e0.z, e0.w,
                                          e1.x, e1.y, e1.z, e1.w };
            unsigned int wt[8];
#pragma unroll
            for (int idx = 0; idx < 8; ++idx) {
                const float Es = bflo(epk[idx]);
                const float Fs = bfhi(epk[idx]);
                const float wv = fmaxf(Es, Fs * rd[hh]);
                const unsigned int bit =
                    (mw[idx >> 1] >> ((idx & 1) ? n16 : n)) & 1u;
                wt[idx] = __float_as_uint(bit ? wv : iEd[hh]);
            }
            uintx4 au;   // v_perm keeps bytes 3:2 of each src = bf16 trunc
            au.x = __builtin_amdgcn_perm(wt[1], wt[0], 0x07060302);
            au.y = __builtin_amdgcn_perm(wt[3], wt[2], 0x07060302);
            au.z = __builtin_amdgcn_perm(wt[5], wt[4], 0x07060302);
            au.w = __builtin_amdgcn_perm(wt[7], wt[6], 0x07060302);
            const short8 As = __builtin_bit_cast(short8, au);
            Cacc[hh] = __builtin_amdgcn_mfma_f32_16x16x32_bf16(
                As, hh ? Bf1 : Bf0, Cacc[hh], 0, 0, 0);
            Cz[hh] = __builtin_amdgcn_mfma_f32_16x16x32_bf16(
                As, onesB, Cz[hh], 0, 0, 0);
        }
        Bf0 = nB0;
        Bf1 = nB1;
    }

    // epilogue: atomically add this conv's full term (Ed cancels in ratio)
#pragma unroll
    for (int hh = 0; hh < 2; ++hh) {
        const int h = h0 + hh;
        const float bv = bias[ij * D_ + h * 16 + n];
        const uint2 sv = *(const uint2*)(xpi + (size_t)(h * 16 + n) * N_ + d0 + q * 4);
        const float selfv[4] = { bflo(sv.x), bfhi(sv.x), bflo(sv.y), bfhi(sv.y) };
#pragma unroll
        for (int reg = 0; reg < 4; ++reg) {
            const float Zi = 1.0f / Cz[hh][reg];
            const float val = Cacc[hh][reg] * Zi + selfv[reg] + bv;
            unsafeAtomicAdd(
                &hout[((size_t)bi * N_ + d0 + q * 4 + reg) * D_ + h * 16 + n], val);
        }
    }
}

// ---------------------------------------------------------------------------
// Kernel 3: in-place mix on d_out (thread owns both i slices of one b).
// ---------------------------------------------------------------------------
__global__ __launch_bounds__(256) void combine_kernel(float* __restrict__ h)
{
    const int idx = blockIdx.x * 256 + threadIdx.x;
    const int b = idx >> 14;
    const int r = idx & 16383;
    float4* p0 = (float4*)h + (size_t)b * 32768 + r;
    float4* p1 = p0 + 16384;
    const float4 a = *p0;
    const float4 o = *p1;
    float4 r0, r1;
    r0.x = 1.5f * a.x + 0.5f * o.x;  r1.x = 1.5f * o.x + 0.5f * a.x;
    r0.y = 1.5f * a.y + 0.5f * o.y;  r1.y = 1.5f * o.y + 0.5f * a.y;
    r0.z = 1.5f * a.z + 0.5f * o.z;  r1.z = 1.5f * o.z + 0.5f * a.z;
    r0.w = 1.5f * a.w + 0.5f * o.w;  r1.w = 1.5f * o.w + 0.5f * a.w;
    *p0 = r0;
    *p1 = r1;
}

extern "C" void kernel_launch(void* const* d_in, const int* in_sizes, int n_in,
                              void* d_out, int out_size, void* d_ws, size_t ws_size,
                              hipStream_t stream)
{
    const float* x   = (const float*)d_in[0];
    const int*   A   = (const int*)d_in[1];
    const float* W   = (const float*)d_in[2];
    const float* pb  = (const float*)d_in[3];
    const float* as_ = (const float*)d_in[4];
    const float* ad_ = (const float*)d_in[5];
    const float* bs  = (const float*)d_in[6];

    unsigned short* xpt = (unsigned short*)d_ws;                 // 8 MB
    unsigned int* sgE = (unsigned int*)(xpt + (size_t)64 * D_ * N_);      // +1 MB
    float2* sgD = (float2*)(sgE + (size_t)64 * 8 * N_);                   // +2 MB
    unsigned short* mg = (unsigned short*)(sgD + (size_t)64 * 8 * N_);    // +2 MB
    float* h = (float*)d_out;

    hipMemsetAsync(d_out, 0, (size_t)out_size * sizeof(float), stream);
    prep_kernel<<<2048, 256, 0, stream>>>(x, W, pb, as_, ad_, A, xpt, sgE, sgD, mg);
    attn_kernel<<<2048, 256, 0, stream>>>(xpt, sgE, sgD, mg, bs, h);
    combine_kernel<<<1024, 256, 0, stream>>>(h);
}

// Round 3
// 152.487 us; speedup vs baseline: 1.0620x; 1.0620x over previous
//
#include <hip/hip_runtime.h>

#define N_ 512
#define D_ 128
#define LOG2E 1.44269504088896f

// ws: [0, 8 MB)        xp_t f16 TRANSPOSED [inst][f=128][s=512]      (8,388,608 B)
//     [8, 8.5 MB)      sgEs u32 [inst][h=8][sp=256]  (Es pairs f16)  (  524,288 B)
//     [8.5, 9 MB)      sgFs u32 [inst][h=8][sp=256]  (Fs pairs f16)  (  524,288 B)
//     [9, 11 MB)       sgD float2 [inst][h=8][s=512] (Ed, Fd fp32)   (2,097,152 B)
//     [11, 13 MB)      mgT u32 [inst][q=4][dst=512][jw=4]            (2,097,152 B)
// Factorized softmax: w = exp(leaky(ss+sd)) = max(Es*Ed, Fs*Fd); per-dst
// scale Ed cancels, K-loop uses w' = max(Es, Fs*rd) via PACKED f16 math
// (v_pk_mul/v_pk_max), masked w' = 1/Ed blended with v_bfi from a 4-entry
// LDS selmask table indexed by per-lane register-resident mask bits.
// No transcendentals, no v_perm repack, no per-chunk mask loads in hot loop.

typedef __attribute__((ext_vector_type(8))) short short8;
typedef __attribute__((ext_vector_type(4))) float floatx4;
typedef __attribute__((ext_vector_type(4))) unsigned int uintx4;
typedef __attribute__((ext_vector_type(2))) _Float16 half2v;
typedef __attribute__((ext_vector_type(8))) _Float16 half8;

#if defined(__has_builtin)
#if __has_builtin(__builtin_amdgcn_exp2f)
#define EXP2F(x) __builtin_amdgcn_exp2f(x)
#else
#define EXP2F(x) exp2f(x)
#endif
#else
#define EXP2F(x) exp2f(x)
#endif

// pack two f32 -> two f16 (v_cvt_pkrtz_f16_f32), low half = first arg.
// NOTE: builtin returns __fp16 ext_vector(2); capture with auto + bit_cast.
__device__ __forceinline__ unsigned int pkh(float a, float b) {
    auto h = __builtin_amdgcn_cvt_pkrtz(a, b);
    return __builtin_bit_cast(unsigned int, h);
}

// ---------------------------------------------------------------------------
// Kernel 1 (fused prep): blocks 0..1023 = proj (f16 MFMA, fused score
// reductions -> Es/Fs packed-pair f16 + Ed/Fd fp32); blocks 1024..1535 =
// maskprep-T (A -> transposed per-(dst,q) bit words for register residency).
// ---------------------------------------------------------------------------
__global__ __launch_bounds__(256) void prep_kernel(
    const float* __restrict__ x, const float* __restrict__ W,
    const float* __restrict__ pb, const float* __restrict__ att_src,
    const float* __restrict__ att_dst, const int* __restrict__ A,
    unsigned short* __restrict__ xpt, unsigned int* __restrict__ sgEs,
    unsigned int* __restrict__ sgFs, float2* __restrict__ sgD,
    unsigned int* __restrict__ mgT)
{
    const int bid0 = blockIdx.x;
    const int t = threadIdx.x;

    if (bid0 >= 1024) {
        // ---- maskprep-T: block = (bi, dstgroup of 128, s-range of 128) ----
        const int bid = bid0 - 1024;           // 0..511
        const int bi = bid >> 4;               // 0..31
        const int rem = bid & 15;
        const int dg = rem >> 2;               // 0..3 : dst group (128 each)
        const int jw = rem & 3;                // word index (s in [128jw,128jw+128))
        const int dp = t & 63, q = t >> 6;
        const int dstb = dg * 128 + dp * 2;
        const int sbase = jw * 128 + q * 8;
        const int* Ab = A + (size_t)bi * N_ * N_ + dstb;
        unsigned int a00 = 0, a01 = 0, a10 = 0, a11 = 0; // [conv][dd]
#pragma unroll
        for (int cp = 0; cp < 4; ++cp) {
#pragma unroll
            for (int i = 0; i < 8; ++i) {
                const int s = sbase + cp * 32 + i;
                const int2 v = *(const int2*)(Ab + (size_t)s * N_);
                const int bitp = cp * 8 + i;
                a00 |= ((0x14u >> v.x) & 1u) << bitp;   // val in {2,4}
                a10 |= ((0x18u >> v.x) & 1u) << bitp;   // val in {3,4}
                a01 |= ((0x14u >> v.y) & 1u) << bitp;
                a11 |= ((0x18u >> v.y) & 1u) << bitp;
            }
        }
        const int i0 = bi * 2;
        mgT[(((size_t)i0 * 4 + q) * 512 + dstb + 0) * 4 + jw] = a00;
        mgT[(((size_t)i0 * 4 + q) * 512 + dstb + 1) * 4 + jw] = a01;
        mgT[(((size_t)(i0 + 1) * 4 + q) * 512 + dstb + 0) * 4 + jw] = a10;
        mgT[(((size_t)(i0 + 1) * 4 + q) * 512 + dstb + 1) * 4 + jw] = a11;
        return;
    }

    // ------------- proj: 2 blocks per (inst, 64-row ntile) -------------
    const int unit = bid0 >> 1;
    const int half = bid0 & 1;
    const int ntile = unit & 7;
    const int inst  = unit >> 3;
    const int j = inst & 1;
    const int bi = inst >> 1;
    const int ij = (bi & 1) * 2 + j;
    const int wave = t >> 6, L = t & 63, n = L & 15, q = L >> 4;

    const int n0w = ntile * 64 + wave * 16;
    const float* xrow = x + ((size_t)bi * N_ + n0w + n) * D_ + q * 8;
    half8 Af[4];
#pragma unroll
    for (int kc = 0; kc < 4; ++kc) {
        const float4 a0 = *(const float4*)(xrow + kc * 32);
        const float4 a1 = *(const float4*)(xrow + kc * 32 + 4);
        uintx4 au;
        au.x = pkh(a0.x, a0.y);
        au.y = pkh(a0.z, a0.w);
        au.z = pkh(a1.x, a1.y);
        au.w = pkh(a1.z, a1.w);
        Af[kc] = __builtin_bit_cast(half8, au);
    }

    const float* wb = W + (size_t)ij * D_ * D_;
#pragma unroll
    for (int ft = 0; ft < 4; ++ft) {
        const int head = half * 4 + ft;
        const int fg = head * 16 + n;
        const float* wrow = wb + (size_t)fg * D_ + q * 8;
        floatx4 C = (floatx4){0.f, 0.f, 0.f, 0.f};
#pragma unroll
        for (int kc = 0; kc < 4; ++kc) {
            const float4 b0 = *(const float4*)(wrow + kc * 32);
            const float4 b1 = *(const float4*)(wrow + kc * 32 + 4);
            uintx4 bu;
            bu.x = pkh(b0.x, b0.y);
            bu.y = pkh(b0.z, b0.w);
            bu.z = pkh(b1.x, b1.y);
            bu.w = pkh(b1.z, b1.w);
            C = __builtin_amdgcn_mfma_f32_16x16x32_f16(
                Af[kc], __builtin_bit_cast(half8, bu), C, 0, 0, 0);
        }
        const float pbv = pb[ij * D_ + fg];
        float xp0 = C[0] + pbv, xp1 = C[1] + pbv;
        float xp2 = C[2] + pbv, xp3 = C[3] + pbv;
        uint2 pk;
        pk.x = pkh(xp0, xp1);
        pk.y = pkh(xp2, xp3);
        *(uint2*)&xpt[((size_t)inst * D_ + fg) * N_ + n0w + q * 4] = pk;

        const float asv = att_src[ij * D_ + fg];
        const float adv = att_dst[ij * D_ + fg];
        float sa0 = xp0 * asv, sa1 = xp1 * asv, sa2 = xp2 * asv, sa3 = xp3 * asv;
        float sb0 = xp0 * adv, sb1 = xp1 * adv, sb2 = xp2 * adv, sb3 = xp3 * adv;
#pragma unroll
        for (int off = 1; off < 16; off <<= 1) {
            sa0 += __shfl_xor(sa0, off); sa1 += __shfl_xor(sa1, off);
            sa2 += __shfl_xor(sa2, off); sa3 += __shfl_xor(sa3, off);
            sb0 += __shfl_xor(sb0, off); sb1 += __shfl_xor(sb1, off);
            sb2 += __shfl_xor(sb2, off); sb3 += __shfl_xor(sb3, off);
        }
        if (n < 4) {
            // n=0: Es pair j0 (sa0,sa1); n=1: Es pair j1 (sa2,sa3);
            // n=2: Fs pair j0;           n=3: Fs pair j1.
            const float vlo = ((n & 1) ? sa2 : sa0) * LOG2E;
            const float vhi = ((n & 1) ? sa3 : sa1) * LOG2E;
            const float sc = (n < 2) ? 1.0f : 0.2f;
            const unsigned int pkv = pkh(EXP2F(sc * vlo), EXP2F(sc * vhi));
            unsigned int* dstp = (n < 2) ? sgEs : sgFs;
            dstp[((size_t)inst * 8 + head) * 256 + (n0w >> 1) + q * 2 + (n & 1)] = pkv;
        } else if (n >= 8 && n < 12) {   // Ed, Fd fp32
            const int r = n - 8;
            const float v = ((r == 0) ? sb0 : (r == 1) ? sb1 : (r == 2) ? sb2 : sb3) * LOG2E;
            float2 ed;
            ed.x = EXP2F(v);
            ed.y = EXP2F(0.2f * v);
            sgD[((size_t)inst * 8 + head) * N_ + n0w + q * 4 + r] = ed;
        }
    }
}

// ---------------------------------------------------------------------------
// Kernel 2: attention via f16 MFMA, packed-pair weight math. 2048 blocks:
// tile = bid&31, conv = (bid>>5)&1, bi = bid>>6. 4 waves, wave owns 2 heads.
// Per chunk: mask bits from registers -> selmask via 4-entry LDS table,
// wv = pk_max(Es, pk_mul(Fs, rd)) [2 VALU / pair], blend via v_bfi. No perm.
// ---------------------------------------------------------------------------
__global__ __launch_bounds__(256) void attn_kernel(
    const unsigned short* __restrict__ xpt,
    const unsigned int* __restrict__ sgEs,
    const unsigned int* __restrict__ sgFs,
    const float2* __restrict__ sgD,
    const unsigned int* __restrict__ mgT,
    const float* __restrict__ bias,
    float* __restrict__ hout)
{
    __shared__ unsigned int es_l[8 * 256];   // 8 KB [h][sp] Es f16 pairs
    __shared__ unsigned int fs_l[8 * 256];   // 8 KB [h][sp] Fs f16 pairs
    __shared__ unsigned int seltab[4];

    const int bid = blockIdx.x;
    const int tile = bid & 31;
    const int cj   = (bid >> 5) & 1;
    const int bi   = bid >> 6;
    const int inst = bi * 2 + cj;
    const int ij = (bi & 1) * 2 + cj;
    const int d0 = tile * 16;
    const int t = threadIdx.x;
    const int wave = t >> 6, L = t & 63, n = L & 15, q = L >> 4;
    const int h0 = wave * 2;

    // stage Es/Fs pair streams (2048 u32 each)
    {
        const uint4* sE = (const uint4*)(sgEs + (size_t)inst * 2048);
        const uint4* sF = (const uint4*)(sgFs + (size_t)inst * 2048);
        ((uint4*)es_l)[t]       = sE[t];
        ((uint4*)es_l)[256 + t] = sE[256 + t];
        ((uint4*)fs_l)[t]       = sF[t];
        ((uint4*)fs_l)[256 + t] = sF[256 + t];
    }
    if (t < 4) seltab[t] = ((t & 1) ? 0x0000FFFFu : 0u) | ((t & 2) ? 0xFFFF0000u : 0u);

    // per-lane mask bits: 128 bits covering (dst=d0+n, this lane's q-slice)
    const uint4 mreg = *(const uint4*)(mgT + (((size_t)inst * 4 + q) * 512 + d0 + n) * 4);
    const unsigned int mw_[4] = { mreg.x, mreg.y, mreg.z, mreg.w };

    // per-(hh) dst factors, packed f16: iEd2 = 1/Ed, rd2 = Fd/Ed
    unsigned int iEd2[2], rd2[2];
#pragma unroll
    for (int hh = 0; hh < 2; ++hh) {
        const float2 ed = sgD[((size_t)inst * 8 + h0 + hh) * N_ + d0 + n];
        const float iEd = 1.0f / ed.x;
        const float rdv = ed.y * iEd;
        iEd2[hh] = pkh(iEd, iEd);
        rd2[hh] = pkh(rdv, rdv);
    }

    __syncthreads();   // the ONLY barrier

    const unsigned short* xpi = xpt + (size_t)inst * D_ * N_;
    const unsigned short* bp0 = xpi + (size_t)(h0 * 16 + n) * N_;
    const unsigned short* bp1 = xpi + (size_t)((h0 + 1) * 16 + n) * N_;

    const uintx4 ou = { 0x3C003C00u, 0x3C003C00u, 0x3C003C00u, 0x3C003C00u };
    const half8 onesB = __builtin_bit_cast(half8, ou);

    floatx4 Cacc[2] = { (floatx4){0.f,0.f,0.f,0.f}, (floatx4){0.f,0.f,0.f,0.f} };
    floatx4 Cz[2]   = { (floatx4){0.f,0.f,0.f,0.f}, (floatx4){0.f,0.f,0.f,0.f} };

    // software-prefetched, barrier-free K loop: 16 chunks of 32 s
    uintx4 B0 = *(const uintx4*)(bp0 + q * 8);
    uintx4 B1 = *(const uintx4*)(bp1 + q * 8);
#pragma unroll
    for (int c = 0; c < 16; ++c) {
        const int sq = c * 32 + q * 8;
        uintx4 nB0, nB1;
        if (c < 15) {
            nB0 = *(const uintx4*)(bp0 + sq + 32);
            nB1 = *(const uintx4*)(bp1 + sq + 32);
        }
        const unsigned int word = mw_[c >> 2];
        unsigned int sel[4];
#pragma unroll
        for (int p = 0; p < 4; ++p) {
            const int sh = (c & 3) * 8 + 2 * p;      // compile-time constant
            const unsigned int b4 = (sh >= 2) ? ((word >> (sh - 2)) & 12u)
                                              : ((word << 2) & 12u);
            sel[p] = *(const unsigned int*)((const char*)seltab + b4);
        }
        const int spb = c * 16 + q * 4;
#pragma unroll
        for (int hh = 0; hh < 2; ++hh) {
            const uint4 Ep = *(const uint4*)&es_l[(h0 + hh) * 256 + spb];
            const uint4 Fp = *(const uint4*)&fs_l[(h0 + hh) * 256 + spb];
            const unsigned int eu[4] = { Ep.x, Ep.y, Ep.z, Ep.w };
            const unsigned int fu[4] = { Fp.x, Fp.y, Fp.z, Fp.w };
            const half2v rdh = __builtin_bit_cast(half2v, rd2[hh]);
            uintx4 au;
            unsigned int wts[4];
#pragma unroll
            for (int p = 0; p < 4; ++p) {
                const half2v e = __builtin_bit_cast(half2v, eu[p]);
                const half2v f = __builtin_bit_cast(half2v, fu[p]);
                const half2v pr = f * rdh;                       // v_pk_mul_f16
                const half2v wv = __builtin_elementwise_max(pr, e); // v_pk_max_f16
                const unsigned int wvu = __builtin_bit_cast(unsigned int, wv);
                wts[p] = (sel[p] & wvu) | (~sel[p] & iEd2[hh]);  // v_bfi
            }
            au.x = wts[0]; au.y = wts[1]; au.z = wts[2]; au.w = wts[3];
            const half8 As = __builtin_bit_cast(half8, au);
            Cacc[hh] = __builtin_amdgcn_mfma_f32_16x16x32_f16(
                As, __builtin_bit_cast(half8, hh ? B1 : B0), Cacc[hh], 0, 0, 0);
            Cz[hh] = __builtin_amdgcn_mfma_f32_16x16x32_f16(
                As, onesB, Cz[hh], 0, 0, 0);
        }
        B0 = nB0;
        B1 = nB1;
    }

    // epilogue: atomically add this conv's full term (Ed cancels in ratio)
#pragma unroll
    for (int hh = 0; hh < 2; ++hh) {
        const int h = h0 + hh;
        const float bv = bias[ij * D_ + h * 16 + n];
        const uint2 sv = *(const uint2*)(xpi + (size_t)(h * 16 + n) * N_ + d0 + q * 4);
        const half2v s0 = __builtin_bit_cast(half2v, sv.x);
        const half2v s1 = __builtin_bit_cast(half2v, sv.y);
        const float selfv[4] = { (float)s0[0], (float)s0[1],
                                 (float)s1[0], (float)s1[1] };
#pragma unroll
        for (int reg = 0; reg < 4; ++reg) {
            const float Zi = 1.0f / Cz[hh][reg];
            const float val = Cacc[hh][reg] * Zi + selfv[reg] + bv;
            unsafeAtomicAdd(
                &hout[((size_t)bi * N_ + d0 + q * 4 + reg) * D_ + h * 16 + n], val);
        }
    }
}

// ---------------------------------------------------------------------------
// Kernel 3: in-place mix on d_out (thread owns both i slices of one b).
// ---------------------------------------------------------------------------
__global__ __launch_bounds__(256) void combine_kernel(float* __restrict__ h)
{
    const int idx = blockIdx.x * 256 + threadIdx.x;
    const int b = idx >> 14;
    const int r = idx & 16383;
    float4* p0 = (float4*)h + (size_t)b * 32768 + r;
    float4* p1 = p0 + 16384;
    const float4 a = *p0;
    const float4 o = *p1;
    float4 r0, r1;
    r0.x = 1.5f * a.x + 0.5f * o.x;  r1.x = 1.5f * o.x + 0.5f * a.x;
    r0.y = 1.5f * a.y + 0.5f * o.y;  r1.y = 1.5f * o.y + 0.5f * a.y;
    r0.z = 1.5f * a.z + 0.5f * o.z;  r1.z = 1.5f * o.z + 0.5f * a.z;
    r0.w = 1.5f * a.w + 0.5f * o.w;  r1.w = 1.5f * o.w + 0.5f * a.w;
    *p0 = r0;
    *p1 = r1;
}

extern "C" void kernel_launch(void* const* d_in, const int* in_sizes, int n_in,
                              void* d_out, int out_size, void* d_ws, size_t ws_size,
                              hipStream_t stream)
{
    const float* x   = (const float*)d_in[0];
    const int*   A   = (const int*)d_in[1];
    const float* W   = (const float*)d_in[2];
    const float* pb  = (const float*)d_in[3];
    const float* as_ = (const float*)d_in[4];
    const float* ad_ = (const float*)d_in[5];
    const float* bs  = (const float*)d_in[6];

    unsigned short* xpt = (unsigned short*)d_ws;                              // 8 MB
    unsigned int* sgEs = (unsigned int*)((char*)d_ws + (8u << 20));           // 512 KB
    unsigned int* sgFs = (unsigned int*)((char*)d_ws + (8u << 20) + (512u << 10)); // 512 KB
    float2* sgD = (float2*)((char*)d_ws + (9u << 20));                        // 2 MB
    unsigned int* mgT = (unsigned int*)((char*)d_ws + (11u << 20));           // 2 MB
    float* h = (float*)d_out;

    (void)hipMemsetAsync(d_out, 0, (size_t)out_size * sizeof(float), stream);
    prep_kernel<<<1536, 256, 0, stream>>>(x, W, pb, as_, ad_, A, xpt, sgEs, sgFs, sgD, mgT);
    attn_kernel<<<2048, 256, 0, stream>>>(xpt, sgEs, sgFs, sgD, mgT, bs, h);
    combine_kernel<<<1024, 256, 0, stream>>>(h);
}